// Round 6
// baseline (54.282 us; speedup 1.0000x reference)
//
#include <hip/hip_runtime.h>
#include <math.h>

typedef _Float16 f16x8 __attribute__((ext_vector_type(8)));
typedef float f32x4 __attribute__((ext_vector_type(4)));

// ---------------------------------------------------------------------------
// Geometry: qry (256c, 16384px) f32; sup_x (5,256,16384) f32; sup_y (5,16384)
// protos M=1280, C=256, PX=16384. out (16384) f32.
// pred[px] = sum_m softmax(mask? d : NEG)_m * d_m, d = 20*<qry_n[px],pro_n[m]>
// d <= 20 -> FIXED-max softmax: e = mk*exp(d-20) in [e^-40, 1]. Masked -> 0.
// pro_h / qn_h stored LINEAR [row][256] f16; K3 streams both global->VGPR.
// ---------------------------------------------------------------------------

// K1: blocks 0..1279 pool plane (s,c) of sup_x -> cand_T[c][s*256+g] (coalesced
//     1KB/block write). Blocks 1280..1284 pool sup_y shot r -> yv_ws.
__global__ __launch_bounds__(256) void pool_kernel(const float* __restrict__ sup_x,
                                                   const float* __restrict__ sup_y,
                                                   float* __restrict__ cand_T,
                                                   float* __restrict__ yv_ws) {
    const int b = blockIdx.x, t = threadIdx.x;
    if (b < 1280) {
        __shared__ float hs[4096];          // [row 128][col4 32] horizontal 4-sums
        const int s = b >> 8, c = b & 255;
        const float4* plane = (const float4*)(sup_x + (size_t)(s * 256 + c) * 16384);
#pragma unroll
        for (int it = 0; it < 16; ++it) {   // contiguous 4KB per issue
            const float4 v = plane[it * 256 + t];
            hs[it * 256 + t] = v.x + v.y + v.z + v.w;
        }
        __syncthreads();
        const int gy = t >> 4, gx = t & 15;
        float sum = 0.f;
#pragma unroll
        for (int rr = 0; rr < 8; ++rr)
            sum += hs[(gy * 8 + rr) * 32 + 2 * gx] + hs[(gy * 8 + rr) * 32 + 2 * gx + 1];
        cand_T[(size_t)c * 1280 + s * 256 + t] = sum * (1.f / 64.f);
    } else {
        const int r = b - 1280;
        const int gy = t >> 4, gx = t & 15;
        const float* base = sup_y + r * 16384 + gy * 1024 + gx * 8;
        float sum = 0.f;
#pragma unroll
        for (int rr = 0; rr < 8; ++rr) {
            const float4 a = *(const float4*)(base + rr * 128);
            const float4 bb = *(const float4*)(base + rr * 128 + 4);
            sum += a.x + a.y + a.z + a.w + bb.x + bb.y + bb.z + bb.w;
        }
        yv_ws[r * 256 + t] = sum * (1.f / 64.f);
    }
}

// K2: blocks 0..19: finalize 64 protos each (mean-center+L2-norm -> pro_h f16).
//     block 20: mask mode + maskf. blocks 21..276: qnorm 64-px tile -> qn_h f16.
__global__ __launch_bounds__(256) void fin_kernel(const float* __restrict__ cand_T,
                                                  const float* __restrict__ yv_ws,
                                                  const float* __restrict__ qry,
                                                  _Float16* __restrict__ pro_h,
                                                  float* __restrict__ maskf,
                                                  _Float16* __restrict__ qn_h) {
    __shared__ float tile[256 * 65];        // 66.6 KB [c][65] padded
    __shared__ float scr[640];
    const int b = blockIdx.x, t = threadIdx.x;

    if (b < 20) {
        const int m0 = b * 64;
        for (int it = 0; it < 64; ++it) {   // 256B-run coalesced loads
            const int idx = it * 256 + t;
            tile[(idx >> 6) * 65 + (idx & 63)] =
                cand_T[(size_t)(idx >> 6) * 1280 + m0 + (idx & 63)];
        }
        __syncthreads();
        {
            const int ml = t & 63, part = t >> 6;
            float s1 = 0.f, s2 = 0.f;
            for (int cc = 0; cc < 64; ++cc) {
                const float x = tile[(part * 64 + cc) * 65 + ml];
                s1 += x; s2 += x * x;
            }
            scr[part * 64 + ml] = s1; scr[256 + part * 64 + ml] = s2;
        }
        __syncthreads();
        if (t < 64) {
            float S1 = 0.f, S2 = 0.f;
            for (int p = 0; p < 4; ++p) { S1 += scr[p * 64 + t]; S2 += scr[256 + p * 64 + t]; }
            const float mu = S1 * (1.f / 256.f);
            const float nrm = sqrtf(fmaxf(S2 - 256.f * mu * mu, 0.f));
            scr[512 + t] = mu; scr[576 + t] = 1.f / fmaxf(nrm, 1e-4f);
        }
        __syncthreads();
        const int ml = t >> 2, q = t & 3;
        const float mu = scr[512 + ml], inv = scr[576 + ml];
#pragma unroll
        for (int u = 0; u < 8; ++u) {
            const int g = u * 4 + q;        // 4 lanes -> 64B contiguous store
            f16x8 hv;
#pragma unroll
            for (int j = 0; j < 8; ++j)
                hv[j] = (_Float16)((tile[(g * 8 + j) * 65 + ml] - mu) * inv);
            *(f16x8*)(pro_h + (size_t)(m0 + ml) * 256 + g * 8) = hv;
        }
    } else if (b == 20) {
        __shared__ int flags[2];
        if (t < 2) flags[t] = 0;
        __syncthreads();
        float yloc[5];
#pragma unroll
        for (int it = 0; it < 5; ++it) {
            const float y = yv_ws[it * 256 + t];
            yloc[it] = y;
            if (y > 0.5f) atomicOr(&flags[0], 1);
            if (y > 0.1f) atomicOr(&flags[1], 1);
        }
        __syncthreads();
        const int mode = flags[0] ? 0 : (flags[1] ? 1 : 2);
#pragma unroll
        for (int it = 0; it < 5; ++it) {
            const float y = yloc[it];
            const float mk = (mode == 0) ? (y > 0.5f ? 1.f : 0.f)
                           : (mode == 1) ? (y > 0.1f ? 1.f : 0.f) : 1.f;
            maskf[it * 256 + t] = mk;
        }
    } else {
        const int px0 = (b - 21) * 64;
        for (int it = 0; it < 16; ++it) {
            const int c = (t >> 4) + it * 16;
            const float4 v = *(const float4*)(qry + (size_t)c * 16384 + px0 + (t & 15) * 4);
            float* dst = tile + c * 65 + (t & 15) * 4;
            dst[0] = v.x; dst[1] = v.y; dst[2] = v.z; dst[3] = v.w;
        }
        __syncthreads();
        {
            const int p = t & 63, part = t >> 6;
            float s1 = 0.f, s2 = 0.f;
            for (int cc = 0; cc < 64; ++cc) {
                const float x = tile[(part * 64 + cc) * 65 + p];
                s1 += x; s2 += x * x;
            }
            scr[part * 64 + p] = s1; scr[256 + part * 64 + p] = s2;
        }
        __syncthreads();
        if (t < 64) {
            float S1 = 0.f, S2 = 0.f;
            for (int p = 0; p < 4; ++p) { S1 += scr[p * 64 + t]; S2 += scr[256 + p * 64 + t]; }
            const float mu = S1 * (1.f / 256.f);
            const float nrm = sqrtf(fmaxf(S2 - 256.f * mu * mu, 0.f));
            scr[512 + t] = mu; scr[576 + t] = 1.f / fmaxf(nrm, 1e-4f);
        }
        __syncthreads();
        const int px = t >> 2, q = t & 3;
        const float mu = scr[512 + px], inv = scr[576 + px];
#pragma unroll
        for (int u = 0; u < 8; ++u) {
            const int g = u * 4 + q;        // 4 lanes -> 64B contiguous store
            f16x8 hv;
#pragma unroll
            for (int j = 0; j < 8; ++j)
                hv[j] = (_Float16)((tile[(g * 8 + j) * 65 + px] - mu) * inv);
            *(f16x8*)(qn_h + (size_t)(px0 + px) * 256 + g * 8) = hv;
        }
    }
}

// one 128-m tile: (optional) prefetch next A into anxt, 32 MFMA with acur,
// fixed-max softmax epilogue.
__device__ __forceinline__ void tile_step(const _Float16* __restrict__ apn,
                                          f16x8 (&acur)[8], f16x8 (&anxt)[8],
                                          const f16x8 (&bfr)[4][8],
                                          const float* __restrict__ ms_tile, int lq,
                                          float (&Sa)[4], float (&Wa)[4]) {
    if (apn) {
#pragma unroll
        for (int ks = 0; ks < 8; ++ks) anxt[ks] = *(const f16x8*)(apn + ks * 32);
    }
    f32x4 acc[4];
#pragma unroll
    for (int p = 0; p < 4; ++p) acc[p] = (f32x4){0.f, 0.f, 0.f, 0.f};
#pragma unroll
    for (int ks = 0; ks < 8; ++ks) {
#pragma unroll
        for (int p = 0; p < 4; ++p)
            acc[p] = __builtin_amdgcn_mfma_f32_16x16x32_f16(acur[ks], bfr[p][ks], acc[p], 0, 0, 0);
    }
    const f32x4 mkv = *(const f32x4*)(ms_tile + lq * 4);
#pragma unroll
    for (int p = 0; p < 4; ++p) {
        float ssum = 0.f, wsum = 0.f;
#pragma unroll
        for (int r = 0; r < 4; ++r) {
            const float d = 20.f * acc[p][r];
            const float e = mkv[r] * __expf(d - 20.f);
            ssum += e; wsum += e * d;
        }
        Sa[p] += ssum; Wa[p] += wsum;
    }
}

// K3: 256 blocks x 512 thr (8 waves). Block: 64 px, all 1280 protos.
// bfr (qry f16) loaded global->reg; A streams global->reg dbuf; masks in LDS.
// No barriers in the main loop.
__global__ __launch_bounds__(512, 2) void main_kernel(const _Float16* __restrict__ qn_h,
                                                      const _Float16* __restrict__ pro_h,
                                                      const float* __restrict__ maskf,
                                                      float* __restrict__ out) {
    __shared__ float ms[1280];
    __shared__ float red[4096];
    const int t = threadIdx.x;
    const int w = t >> 6, l = t & 63;
    const int ln = l & 15, lq = l >> 4;
    const int px0 = blockIdx.x * 64;

#pragma unroll
    for (int it = 0; it < 3; ++it) {
        const int idx = it * 512 + t;
        if (idx < 1280) ms[idx] = maskf[idx];
    }

    // B (qry) fragments: 4 px-blocks x 8 k-chunks from global
    f16x8 bfr[4][8];
#pragma unroll
    for (int p = 0; p < 4; ++p) {
#pragma unroll
        for (int ks = 0; ks < 8; ++ks)
            bfr[p][ks] = *(const f16x8*)(qn_h + (size_t)(px0 + p * 16 + ln) * 256 + ks * 32 + lq * 8);
    }

    const _Float16* ap = pro_h + (size_t)(w * 16 + ln) * 256 + lq * 8;
    f16x8 aA[8], aB[8];
#pragma unroll
    for (int ks = 0; ks < 8; ++ks) aA[ks] = *(const f16x8*)(ap + ks * 32);

    __syncthreads();   // ms ready

    float Sa[4] = {0.f, 0.f, 0.f, 0.f}, Wa[4] = {0.f, 0.f, 0.f, 0.f};
    const int mbase = w * 16;
#pragma unroll 1
    for (int ii = 0; ii < 5; ++ii) {
        tile_step(ap + 32768, aA, aB, bfr, ms + (2 * ii) * 128 + mbase, lq, Sa, Wa);
        tile_step(ii < 4 ? ap + 2 * 32768 : nullptr, aB, aA, bfr,
                  ms + (2 * ii + 1) * 128 + mbase, lq, Sa, Wa);
        ap += 2 * 32768;
    }

    // merge: 32 (w,lq) slots per px, rotated for conflict-free final read
#pragma unroll
    for (int p = 0; p < 4; ++p) {
        const int px = p * 16 + ln;
        const int slot = (w * 4 + lq + px) & 31;
        red[px * 32 + slot] = Sa[p];
        red[2048 + px * 32 + slot] = Wa[p];
    }
    __syncthreads();
    if (t < 64) {
        float S = 0.f, W = 0.f;
        for (int s = 0; s < 32; ++s) {
            const int slot = (s + t) & 31;
            S += red[t * 32 + slot];
            W += red[2048 + t * 32 + slot];
        }
        out[px0 + t] = W / S;
    }
}

extern "C" void kernel_launch(void* const* d_in, const int* in_sizes, int n_in,
                              void* d_out, int out_size, void* d_ws, size_t ws_size,
                              hipStream_t stream) {
    const float* qry   = (const float*)d_in[0];   // 256*16384
    const float* sup_x = (const float*)d_in[1];   // 5*256*16384
    const float* sup_y = (const float*)d_in[2];   // 5*16384
    float* out = (float*)d_out;                   // 16384

    char* ws = (char*)d_ws;
    float*     cand_T = (float*)ws;               ws += 256 * 1280 * 4;    // 1.25 MB
    float*     yv_ws  = (float*)ws;               ws += 1280 * 4;
    float*     maskf  = (float*)ws;               ws += 1280 * 4;
    _Float16*  pro_h  = (_Float16*)ws;            ws += 1280 * 256 * 2;    // 640 KB
    _Float16*  qn_h   = (_Float16*)ws;            /* 16384*256*2 = 8 MB */

    pool_kernel<<<1285, 256, 0, stream>>>(sup_x, sup_y, cand_T, yv_ws);
    fin_kernel<<<277, 256, 0, stream>>>(cand_T, yv_ws, qry, pro_h, maskf, qn_h);
    main_kernel<<<256, 512, 0, stream>>>(qn_h, pro_h, maskf, out);
}

// Round 7
// 43.840 us; speedup vs baseline: 1.2382x; 1.2382x over previous
//
#include <hip/hip_runtime.h>
#include <math.h>

typedef _Float16 f16x8 __attribute__((ext_vector_type(8)));
typedef float f32x4 __attribute__((ext_vector_type(4)));

// ---------------------------------------------------------------------------
// Geometry: qry (256c, 16384px) f32; sup_x (5,256,16384) f32; sup_y (5,16384)
// protos M=1280, C=256, PX=16384. out (16384) f32.
// pred[px] = sum_m softmax(mask? d : NEG)_m * d_m, d = 20*<qry_n[px],pro_n[m]>
// d <= 20 -> FIXED-max softmax: e = mk*exp(d-20) in [e^-40, 1]. Masked -> 0.
// pro_h PRE-SWIZZLED in global: row m, 16B chunk g stored at g ^ ((m&7)<<2)
// -> main stages tiles LINEARLY via global_load_lds (2-deep, counted vmcnt)
// and ds_read_b128 with the same XOR lands conflict-free (8-cyc b128 floor).
// ---------------------------------------------------------------------------

// K1: blocks 0..1279 pool plane (s,c) of sup_x -> cand_T[c][s*256+g] (coalesced
//     1KB/block write). Blocks 1280..1284 pool sup_y shot r -> yv_ws.
__global__ __launch_bounds__(256) void pool_kernel(const float* __restrict__ sup_x,
                                                   const float* __restrict__ sup_y,
                                                   float* __restrict__ cand_T,
                                                   float* __restrict__ yv_ws) {
    const int b = blockIdx.x, t = threadIdx.x;
    if (b < 1280) {
        __shared__ float hs[4096];          // [row 128][col4 32] horizontal 4-sums
        const int s = b >> 8, c = b & 255;
        const float4* plane = (const float4*)(sup_x + (size_t)(s * 256 + c) * 16384);
#pragma unroll
        for (int it = 0; it < 16; ++it) {   // contiguous 4KB per issue
            const float4 v = plane[it * 256 + t];
            hs[it * 256 + t] = v.x + v.y + v.z + v.w;
        }
        __syncthreads();
        const int gy = t >> 4, gx = t & 15;
        float sum = 0.f;
#pragma unroll
        for (int rr = 0; rr < 8; ++rr)
            sum += hs[(gy * 8 + rr) * 32 + 2 * gx] + hs[(gy * 8 + rr) * 32 + 2 * gx + 1];
        cand_T[(size_t)c * 1280 + s * 256 + t] = sum * (1.f / 64.f);
    } else {
        const int r = b - 1280;
        const int gy = t >> 4, gx = t & 15;
        const float* base = sup_y + r * 16384 + gy * 1024 + gx * 8;
        float sum = 0.f;
#pragma unroll
        for (int rr = 0; rr < 8; ++rr) {
            const float4 a = *(const float4*)(base + rr * 128);
            const float4 bb = *(const float4*)(base + rr * 128 + 4);
            sum += a.x + a.y + a.z + a.w + bb.x + bb.y + bb.z + bb.w;
        }
        yv_ws[r * 256 + t] = sum * (1.f / 64.f);
    }
}

// K2: blocks 0..19 finalize 64 protos each -> pro_h f16 (global-swizzled);
//     block 20: mask mode + maskf.
__global__ __launch_bounds__(256) void fin_kernel(const float* __restrict__ cand_T,
                                                  const float* __restrict__ yv_ws,
                                                  _Float16* __restrict__ pro_h,
                                                  float* __restrict__ maskf) {
    const int b = blockIdx.x, t = threadIdx.x;
    if (b < 20) {
        __shared__ float tile[256 * 65];    // [c][65] padded
        __shared__ float scr[640];
        const int m0 = b * 64;
        for (int it = 0; it < 64; ++it) {
            const int idx = it * 256 + t;
            tile[(idx >> 6) * 65 + (idx & 63)] =
                cand_T[(size_t)(idx >> 6) * 1280 + m0 + (idx & 63)];
        }
        __syncthreads();
        {
            const int ml = t & 63, part = t >> 6;
            float s1 = 0.f, s2 = 0.f;
            for (int cc = 0; cc < 64; ++cc) {
                const float x = tile[(part * 64 + cc) * 65 + ml];
                s1 += x; s2 += x * x;
            }
            scr[part * 64 + ml] = s1; scr[256 + part * 64 + ml] = s2;
        }
        __syncthreads();
        if (t < 64) {
            float S1 = 0.f, S2 = 0.f;
            for (int p = 0; p < 4; ++p) { S1 += scr[p * 64 + t]; S2 += scr[256 + p * 64 + t]; }
            const float mu = S1 * (1.f / 256.f);
            const float nrm = sqrtf(fmaxf(S2 - 256.f * mu * mu, 0.f));
            scr[512 + t] = mu; scr[576 + t] = 1.f / fmaxf(nrm, 1e-4f);
        }
        __syncthreads();
        const int ml = t >> 2, q = t & 3;
        const float mu = scr[512 + ml], inv = scr[576 + ml];
#pragma unroll
        for (int u = 0; u < 8; ++u) {
            const int g = u * 4 + q;
            f16x8 hv;
#pragma unroll
            for (int j = 0; j < 8; ++j)
                hv[j] = (_Float16)((tile[(g * 8 + j) * 65 + ml] - mu) * inv);
            *(f16x8*)(pro_h + (size_t)(m0 + ml) * 256 + ((g ^ ((ml & 7) << 2)) << 3)) = hv;
        }
    } else {
        __shared__ int flags[2];
        if (t < 2) flags[t] = 0;
        __syncthreads();
        float yloc[5];
#pragma unroll
        for (int it = 0; it < 5; ++it) {
            const float y = yv_ws[it * 256 + t];
            yloc[it] = y;
            if (y > 0.5f) atomicOr(&flags[0], 1);
            if (y > 0.1f) atomicOr(&flags[1], 1);
        }
        __syncthreads();
        const int mode = flags[0] ? 0 : (flags[1] ? 1 : 2);
#pragma unroll
        for (int it = 0; it < 5; ++it) {
            const float y = yloc[it];
            maskf[it * 256 + t] = (mode == 0) ? (y > 0.5f ? 1.f : 0.f)
                                : (mode == 1) ? (y > 0.1f ? 1.f : 0.f) : 1.f;
        }
    }
}

__device__ __forceinline__ void gload_lds16h(const _Float16* g, _Float16* l) {
    __builtin_amdgcn_global_load_lds((const __attribute__((address_space(1))) unsigned int*)g,
                                     (__attribute__((address_space(3))) unsigned int*)l,
                                     16, 0, 0);
}
__device__ __forceinline__ void gload_lds16f(const float* g, float* l) {
    __builtin_amdgcn_global_load_lds((const __attribute__((address_space(1))) unsigned int*)g,
                                     (__attribute__((address_space(3))) unsigned int*)l,
                                     16, 0, 0);
}

// stage one 128m x 256c f16 tile (64 KB) linearly: 8 gload_lds per thread
__device__ __forceinline__ void stage_tile(const _Float16* __restrict__ pro_h,
                                           int tile, _Float16* dst, int w, int l) {
#pragma unroll
    for (int i = 0; i < 8; ++i) {
        const int off = w * 4096 + i * 512 + l * 8;
        gload_lds16h(pro_h + (size_t)tile * 32768 + off, dst + off);
    }
}

// compute one 128-m tile: wave owns rows w*16..w*16+15 (unique), all 64 px.
__device__ __forceinline__ void compute_tile(const _Float16* __restrict__ pb,
                                             const float* __restrict__ msp,
                                             const f16x8 (&bfr)[4][8],
                                             int row, int ln7, int lq,
                                             float (&Sa)[4], float (&Wa)[4]) {
    f32x4 acc[4];
#pragma unroll
    for (int p = 0; p < 4; ++p) acc[p] = (f32x4){0.f, 0.f, 0.f, 0.f};
#pragma unroll
    for (int ks = 0; ks < 8; ++ks) {
        const int ch = (ks * 4 + lq) ^ (ln7 << 2);
        const f16x8 a = *(const f16x8*)(pb + row * 256 + ch * 8);
#pragma unroll
        for (int p = 0; p < 4; ++p)
            acc[p] = __builtin_amdgcn_mfma_f32_16x16x32_f16(a, bfr[p][ks], acc[p], 0, 0, 0);
    }
    const f32x4 mkv = *(const f32x4*)(msp + lq * 4);
#pragma unroll
    for (int p = 0; p < 4; ++p) {
        float ssum = 0.f, wsum = 0.f;
#pragma unroll
        for (int r = 0; r < 4; ++r) {
            const float d = 20.f * acc[p][r];
            const float e = mkv[r] * __expf(d - 20.f);
            ssum += e; wsum += e * d;
        }
        Sa[p] += ssum; Wa[p] += wsum;
    }
}

// K3: 256 blocks x 512 thr (8 waves), 1 block/CU. Block: 64 px, all 1280 m.
// Prologue: gload_lds qry -> qtf, normalize -> qs f16 (XOR ^(px&7)), hoist 32
// B-frags/wave to regs. Main: 10 tiles of 128 m, LDS double-buffer staged by
// global_load_lds with counted vmcnt(8) + raw barriers (loads span phases).
__global__ __launch_bounds__(512, 2) void main_kernel(const float* __restrict__ qry,
                                                      const _Float16* __restrict__ pro_h,
                                                      const float* __restrict__ maskf,
                                                      float* __restrict__ out) {
    __shared__ __align__(16) _Float16 arena[65536];   // 128 KB: bufs / qtf / qs / red
    __shared__ float ms[1280];
    __shared__ float scr[1024];
    __shared__ float2 stats[64];

    float*     qtf  = (float*)arena;        // 64 KB [c][64px] (prologue)
    _Float16*  qs   = arena + 32768;        // 32 KB (prologue)
    _Float16*  buf0 = arena;                // 64 KB (main)
    _Float16*  buf1 = arena + 32768;        // 64 KB (main)
    float*     red  = (float*)arena;        // 16 KB (epilogue)

    const int t = threadIdx.x;
    const int w = t >> 6, l = t & 63;
    const int ln = l & 15, lq = l >> 4;
    const int ln7 = ln & 7;
    const int px0 = blockIdx.x * 64;

    // ---- prologue: stage qry tile + masks ----
#pragma unroll
    for (int i = 0; i < 8; ++i) {
        const int c = i * 32 + (t >> 4);
        gload_lds16f(qry + (size_t)c * 16384 + px0 + (t & 15) * 4,
                     qtf + i * 2048 + t * 4);
    }
#pragma unroll
    for (int it = 0; it < 3; ++it) {
        const int idx = it * 512 + t;
        if (idx < 1280) ms[idx] = maskf[idx];
    }
    __syncthreads();   // full drain: qtf + ms ready
    {   // per-px partials
        const int p = t & 63, q = t >> 6;
        float s1 = 0.f, s2 = 0.f;
        for (int cc = 0; cc < 32; ++cc) {
            const float x = qtf[(q * 32 + cc) * 64 + p];
            s1 += x; s2 += x * x;
        }
        scr[q * 64 + p] = s1; scr[512 + q * 64 + p] = s2;
    }
    __syncthreads();
    if (t < 64) {
        float S1 = 0.f, S2 = 0.f;
        for (int q = 0; q < 8; ++q) { S1 += scr[q * 64 + t]; S2 += scr[512 + q * 64 + t]; }
        const float mu = S1 * (1.f / 256.f);
        const float nrm = sqrtf(fmaxf(S2 - 256.f * mu * mu, 0.f));
        stats[t] = make_float2(mu, 1.f / fmaxf(nrm, 1e-4f));
    }
    __syncthreads();
    {   // normalize -> qs f16, chunk g at g ^ (px&7)
        const int px = t & 63, e = t >> 6;
        const float2 st = stats[px];
#pragma unroll
        for (int u = 0; u < 4; ++u) {
            const int g = e * 4 + u;
            f16x8 hv;
#pragma unroll
            for (int j = 0; j < 8; ++j)
                hv[j] = (_Float16)((qtf[(g * 8 + j) * 64 + px] - st.x) * st.y);
            *(f16x8*)(qs + px * 256 + ((g ^ (px & 7)) << 3)) = hv;
        }
    }
    __syncthreads();   // qs ready (qtf dead)

    // ---- hoist B fragments to registers ----
    f16x8 bfr[4][8];
#pragma unroll
    for (int p = 0; p < 4; ++p) {
        const int px = p * 16 + ln;
        const int sB = px & 7;
#pragma unroll
        for (int ks = 0; ks < 8; ++ks) {
            const int g = ks * 4 + lq;
            bfr[p][ks] = *(const f16x8*)(qs + px * 256 + ((g ^ sB) << 3));
        }
    }
    __syncthreads();   // ALL waves done reading qs -> arena free for buffers

    // ---- prime the pipeline: stage tiles 0,1 (16 loads in flight/wave) ----
    stage_tile(pro_h, 0, buf0, w, l);
    stage_tile(pro_h, 1, buf1, w, l);

    const int row = w * 16 + ln;
    float Sa[4] = {0.f, 0.f, 0.f, 0.f}, Wa[4] = {0.f, 0.f, 0.f, 0.f};

#pragma unroll 1
    for (int tile = 0; tile < 9; ++tile) {
        asm volatile("s_waitcnt vmcnt(8)" ::: "memory");   // tile's 8 done; next 8 fly
        __builtin_amdgcn_s_barrier();
        compute_tile((tile & 1) ? buf1 : buf0, ms + tile * 128 + w * 16,
                     bfr, row, ln7, lq, Sa, Wa);
        __builtin_amdgcn_s_barrier();                      // all reads of this buf done
        asm volatile("" ::: "memory");
        if (tile < 8)
            stage_tile(pro_h, tile + 2, (tile & 1) ? buf1 : buf0, w, l);
    }
    asm volatile("s_waitcnt vmcnt(0)" ::: "memory");       // last tile (9) staged
    __builtin_amdgcn_s_barrier();
    compute_tile(buf1, ms + 9 * 128 + w * 16, bfr, row, ln7, lq, Sa, Wa);

    // ---- merge: 32 (w,lq) slots per px (red overlays buf0; tile 9 = buf1) ----
#pragma unroll
    for (int p = 0; p < 4; ++p) {
        const int px = p * 16 + ln;
        const int slot = (w * 4 + lq + px) & 31;
        red[px * 32 + slot] = Sa[p];
        red[2048 + px * 32 + slot] = Wa[p];
    }
    __syncthreads();
    if (t < 64) {
        float S = 0.f, W = 0.f;
        for (int s = 0; s < 32; ++s) {
            const int slot = (s + t) & 31;
            S += red[t * 32 + slot];
            W += red[2048 + t * 32 + slot];
        }
        out[px0 + t] = W / S;
    }
}

extern "C" void kernel_launch(void* const* d_in, const int* in_sizes, int n_in,
                              void* d_out, int out_size, void* d_ws, size_t ws_size,
                              hipStream_t stream) {
    const float* qry   = (const float*)d_in[0];   // 256*16384
    const float* sup_x = (const float*)d_in[1];   // 5*256*16384
    const float* sup_y = (const float*)d_in[2];   // 5*16384
    float* out = (float*)d_out;                   // 16384

    char* ws = (char*)d_ws;
    float*     cand_T = (float*)ws;               ws += 256 * 1280 * 4;    // 1.25 MB
    float*     yv_ws  = (float*)ws;               ws += 1280 * 4;
    float*     maskf  = (float*)ws;               ws += 1280 * 4;
    _Float16*  pro_h  = (_Float16*)ws;            /* 640 KB */

    pool_kernel<<<1285, 256, 0, stream>>>(sup_x, sup_y, cand_T, yv_ws);
    fin_kernel<<<21, 256, 0, stream>>>(cand_T, yv_ws, pro_h, maskf);
    main_kernel<<<256, 512, 0, stream>>>(qry, pro_h, maskf, out);
}

// Round 8
// 41.993 us; speedup vs baseline: 1.2926x; 1.0440x over previous
//
#include <hip/hip_runtime.h>
#include <math.h>

typedef _Float16 f16x8 __attribute__((ext_vector_type(8)));
typedef float f32x4 __attribute__((ext_vector_type(4)));

// ---------------------------------------------------------------------------
// Geometry: qry (256c, 16384px) f32; sup_x (5,256,16384) f32; sup_y (5,16384)
// protos M=1280, C=256, PX=16384. out (16384) f32.
// pred[px] = sum_m softmax(mask? d : NEG)_m * d_m, d = 20*<qry_n[px],pro_n[m]>
// d <= 20 -> FIXED-max softmax: e = mk*exp(d-20) in [e^-40, 1]. Masked -> 0.
// pro_h PRE-SWIZZLED in global: row m, 16B chunk g stored at g ^ (m&7)
// (byte bits 4-6 -> bank bits 2-4: consecutive-lane b128 reads tile all 32
// banks, conflict-free). Main stages tiles LINEARLY via global_load_lds,
// 2-deep double buffer, per-wave counted vmcnt (wave stages+reads only its
// own 8KB slice -> no inter-wave barriers needed in the loop).
// ---------------------------------------------------------------------------

// K1: blocks 0..1279 pool plane (s,c) of sup_x -> cand_T[c][s*256+g] (coalesced
//     1KB/block write). Blocks 1280..1284 pool sup_y shot r -> yv_ws.
__global__ __launch_bounds__(256) void pool_kernel(const float* __restrict__ sup_x,
                                                   const float* __restrict__ sup_y,
                                                   float* __restrict__ cand_T,
                                                   float* __restrict__ yv_ws) {
    const int b = blockIdx.x, t = threadIdx.x;
    if (b < 1280) {
        __shared__ float hs[4096];          // [row 128][col4 32] horizontal 4-sums
        const int s = b >> 8, c = b & 255;
        const float4* plane = (const float4*)(sup_x + (size_t)(s * 256 + c) * 16384);
#pragma unroll
        for (int it = 0; it < 16; ++it) {   // contiguous 4KB per issue
            const float4 v = plane[it * 256 + t];
            hs[it * 256 + t] = v.x + v.y + v.z + v.w;
        }
        __syncthreads();
        const int gy = t >> 4, gx = t & 15;
        float sum = 0.f;
#pragma unroll
        for (int rr = 0; rr < 8; ++rr)
            sum += hs[(gy * 8 + rr) * 32 + 2 * gx] + hs[(gy * 8 + rr) * 32 + 2 * gx + 1];
        cand_T[(size_t)c * 1280 + s * 256 + t] = sum * (1.f / 64.f);
    } else {
        const int r = b - 1280;
        const int gy = t >> 4, gx = t & 15;
        const float* base = sup_y + r * 16384 + gy * 1024 + gx * 8;
        float sum = 0.f;
#pragma unroll
        for (int rr = 0; rr < 8; ++rr) {
            const float4 a = *(const float4*)(base + rr * 128);
            const float4 bb = *(const float4*)(base + rr * 128 + 4);
            sum += a.x + a.y + a.z + a.w + bb.x + bb.y + bb.z + bb.w;
        }
        yv_ws[r * 256 + t] = sum * (1.f / 64.f);
    }
}

// K2: blocks 0..19 finalize 64 protos each -> pro_h f16 (global-swizzled);
//     block 20: mask mode + maskf.
__global__ __launch_bounds__(256) void fin_kernel(const float* __restrict__ cand_T,
                                                  const float* __restrict__ yv_ws,
                                                  _Float16* __restrict__ pro_h,
                                                  float* __restrict__ maskf) {
    const int b = blockIdx.x, t = threadIdx.x;
    if (b < 20) {
        __shared__ float tile[256 * 65];    // [c][65] padded
        __shared__ float scr[640];
        const int m0 = b * 64;
        for (int it = 0; it < 64; ++it) {
            const int idx = it * 256 + t;
            tile[(idx >> 6) * 65 + (idx & 63)] =
                cand_T[(size_t)(idx >> 6) * 1280 + m0 + (idx & 63)];
        }
        __syncthreads();
        {
            const int ml = t & 63, part = t >> 6;
            float s1 = 0.f, s2 = 0.f;
            for (int cc = 0; cc < 64; ++cc) {
                const float x = tile[(part * 64 + cc) * 65 + ml];
                s1 += x; s2 += x * x;
            }
            scr[part * 64 + ml] = s1; scr[256 + part * 64 + ml] = s2;
        }
        __syncthreads();
        if (t < 64) {
            float S1 = 0.f, S2 = 0.f;
            for (int p = 0; p < 4; ++p) { S1 += scr[p * 64 + t]; S2 += scr[256 + p * 64 + t]; }
            const float mu = S1 * (1.f / 256.f);
            const float nrm = sqrtf(fmaxf(S2 - 256.f * mu * mu, 0.f));
            scr[512 + t] = mu; scr[576 + t] = 1.f / fmaxf(nrm, 1e-4f);
        }
        __syncthreads();
        const int ml = t >> 2, q = t & 3;
        const float mu = scr[512 + ml], inv = scr[576 + ml];
#pragma unroll
        for (int u = 0; u < 8; ++u) {
            const int g = u * 4 + q;
            f16x8 hv;
#pragma unroll
            for (int j = 0; j < 8; ++j)
                hv[j] = (_Float16)((tile[(g * 8 + j) * 65 + ml] - mu) * inv);
            *(f16x8*)(pro_h + (size_t)(m0 + ml) * 256 + ((g ^ (ml & 7)) << 3)) = hv;
        }
    } else {
        __shared__ int flags[2];
        if (t < 2) flags[t] = 0;
        __syncthreads();
        float yloc[5];
#pragma unroll
        for (int it = 0; it < 5; ++it) {
            const float y = yv_ws[it * 256 + t];
            yloc[it] = y;
            if (y > 0.5f) atomicOr(&flags[0], 1);
            if (y > 0.1f) atomicOr(&flags[1], 1);
        }
        __syncthreads();
        const int mode = flags[0] ? 0 : (flags[1] ? 1 : 2);
#pragma unroll
        for (int it = 0; it < 5; ++it) {
            const float y = yloc[it];
            maskf[it * 256 + t] = (mode == 0) ? (y > 0.5f ? 1.f : 0.f)
                                : (mode == 1) ? (y > 0.1f ? 1.f : 0.f) : 1.f;
        }
    }
}

__device__ __forceinline__ void gload_lds16h(const _Float16* g, _Float16* l) {
    __builtin_amdgcn_global_load_lds((const __attribute__((address_space(1))) unsigned int*)g,
                                     (__attribute__((address_space(3))) unsigned int*)l,
                                     16, 0, 0);
}
__device__ __forceinline__ void gload_lds16f(const float* g, float* l) {
    __builtin_amdgcn_global_load_lds((const __attribute__((address_space(1))) unsigned int*)g,
                                     (__attribute__((address_space(3))) unsigned int*)l,
                                     16, 0, 0);
}

// stage one 128m x 256c f16 tile: wave w stages ITS OWN 16 rows (8KB slice)
__device__ __forceinline__ void stage_tile(const _Float16* __restrict__ pro_h,
                                           int tile, _Float16* dst, int w, int l) {
#pragma unroll
    for (int i = 0; i < 8; ++i) {
        const int off = w * 4096 + i * 512 + l * 8;
        gload_lds16h(pro_h + (size_t)tile * 32768 + off, dst + off);
    }
}

// compute one 128-m tile: wave owns rows w*16..w*16+15 (its own slice).
__device__ __forceinline__ void compute_tile(const _Float16* __restrict__ pb,
                                             const float* __restrict__ msp,
                                             const f16x8 (&bfr)[4][8],
                                             int row, int ln7, int lq,
                                             float (&Sa)[4], float (&Wa)[4]) {
    f32x4 acc[4];
#pragma unroll
    for (int p = 0; p < 4; ++p) acc[p] = (f32x4){0.f, 0.f, 0.f, 0.f};
#pragma unroll
    for (int ks = 0; ks < 8; ++ks) {
        const int ch = (ks * 4 + lq) ^ ln7;          // bank-correct swizzle
        const f16x8 a = *(const f16x8*)(pb + row * 256 + ch * 8);
#pragma unroll
        for (int p = 0; p < 4; ++p)
            acc[p] = __builtin_amdgcn_mfma_f32_16x16x32_f16(a, bfr[p][ks], acc[p], 0, 0, 0);
    }
    const f32x4 mkv = *(const f32x4*)(msp + lq * 4);
#pragma unroll
    for (int p = 0; p < 4; ++p) {
        float ssum = 0.f, wsum = 0.f;
#pragma unroll
        for (int r = 0; r < 4; ++r) {
            const float d = 20.f * acc[p][r];
            const float e = mkv[r] * __expf(d - 20.f);
            ssum += e; wsum += e * d;
        }
        Sa[p] += ssum; Wa[p] += wsum;
    }
}

// K3: 256 blocks x 512 thr (8 waves), 1 block/CU. Block: 64 px, all 1280 m.
// Prologue: gload_lds qry -> qtf, normalize -> qs f16 (XOR ^(px&7)), hoist 32
// B-frags/wave to regs. Main: 10 tiles of 128 m, LDS dbuf staged per-wave by
// global_load_lds with counted vmcnt(8); NO inter-wave barriers in the loop.
__global__ __launch_bounds__(512, 2) void main_kernel(const float* __restrict__ qry,
                                                      const _Float16* __restrict__ pro_h,
                                                      const float* __restrict__ maskf,
                                                      float* __restrict__ out) {
    __shared__ __align__(16) _Float16 arena[65536];   // 128 KB: bufs / qtf / qs / red
    __shared__ float ms[1280];
    __shared__ float scr[1024];
    __shared__ float2 stats[64];

    float*     qtf  = (float*)arena;        // 64 KB [c][64px] (prologue)
    _Float16*  qs   = arena + 32768;        // 32 KB (prologue)
    _Float16*  buf0 = arena;                // 64 KB (main)
    _Float16*  buf1 = arena + 32768;        // 64 KB (main)
    float*     red  = (float*)arena;        // 16 KB (epilogue, overlays buf0)

    const int t = threadIdx.x;
    const int w = t >> 6, l = t & 63;
    const int ln = l & 15, lq = l >> 4;
    const int ln7 = ln & 7;
    const int px0 = blockIdx.x * 64;

    // ---- prologue: stage qry tile + masks ----
#pragma unroll
    for (int i = 0; i < 8; ++i) {
        const int c = i * 32 + (t >> 4);
        gload_lds16f(qry + (size_t)c * 16384 + px0 + (t & 15) * 4,
                     qtf + i * 2048 + t * 4);
    }
#pragma unroll
    for (int it = 0; it < 3; ++it) {
        const int idx = it * 512 + t;
        if (idx < 1280) ms[idx] = maskf[idx];
    }
    __syncthreads();   // full drain: qtf + ms ready
    {   // per-px partials
        const int p = t & 63, q = t >> 6;
        float s1 = 0.f, s2 = 0.f;
        for (int cc = 0; cc < 32; ++cc) {
            const float x = qtf[(q * 32 + cc) * 64 + p];
            s1 += x; s2 += x * x;
        }
        scr[q * 64 + p] = s1; scr[512 + q * 64 + p] = s2;
    }
    __syncthreads();
    if (t < 64) {
        float S1 = 0.f, S2 = 0.f;
        for (int q = 0; q < 8; ++q) { S1 += scr[q * 64 + t]; S2 += scr[512 + q * 64 + t]; }
        const float mu = S1 * (1.f / 256.f);
        const float nrm = sqrtf(fmaxf(S2 - 256.f * mu * mu, 0.f));
        stats[t] = make_float2(mu, 1.f / fmaxf(nrm, 1e-4f));
    }
    __syncthreads();
    {   // normalize -> qs f16, chunk g at g ^ (px&7)
        const int px = t & 63, e = t >> 6;
        const float2 st = stats[px];
#pragma unroll
        for (int u = 0; u < 4; ++u) {
            const int g = e * 4 + u;
            f16x8 hv;
#pragma unroll
            for (int j = 0; j < 8; ++j)
                hv[j] = (_Float16)((qtf[(g * 8 + j) * 64 + px] - st.x) * st.y);
            *(f16x8*)(qs + px * 256 + ((g ^ (px & 7)) << 3)) = hv;
        }
    }
    __syncthreads();   // qs ready (qtf dead)

    // ---- hoist B fragments to registers ----
    f16x8 bfr[4][8];
#pragma unroll
    for (int p = 0; p < 4; ++p) {
        const int px = p * 16 + ln;
        const int sB = px & 7;
#pragma unroll
        for (int ks = 0; ks < 8; ++ks) {
            const int g = ks * 4 + lq;
            bfr[p][ks] = *(const f16x8*)(qs + px * 256 + ((g ^ sB) << 3));
        }
    }
    __syncthreads();   // ALL waves done reading qs -> arena free for buffers

    // ---- per-wave 2-deep pipeline (no inter-wave barriers) ----
    stage_tile(pro_h, 0, buf0, w, l);
    stage_tile(pro_h, 1, buf1, w, l);

    const int row = w * 16 + ln;
    float Sa[4] = {0.f, 0.f, 0.f, 0.f}, Wa[4] = {0.f, 0.f, 0.f, 0.f};

#pragma unroll 1
    for (int tile = 0; tile < 10; ++tile) {
        if (tile < 8) asm volatile("s_waitcnt vmcnt(8)" ::: "memory");
        else          asm volatile("s_waitcnt vmcnt(0)" ::: "memory");
        compute_tile((tile & 1) ? buf1 : buf0, ms + tile * 128 + w * 16,
                     bfr, row, ln7, lq, Sa, Wa);
        if (tile < 8) {
            // all ds_reads of this buffer retired before we overwrite it
            asm volatile("s_waitcnt lgkmcnt(0)" ::: "memory");
            __builtin_amdgcn_sched_barrier(0);
            stage_tile(pro_h, tile + 2, (tile & 1) ? buf1 : buf0, w, l);
        }
    }

    __syncthreads();   // all waves done with buffers -> red overlay safe
#pragma unroll
    for (int p = 0; p < 4; ++p) {
        const int px = p * 16 + ln;
        const int slot = (w * 4 + lq + px) & 31;
        red[px * 32 + slot] = Sa[p];
        red[2048 + px * 32 + slot] = Wa[p];
    }
    __syncthreads();
    if (t < 64) {
        float S = 0.f, W = 0.f;
        for (int s = 0; s < 32; ++s) {
            const int slot = (s + t) & 31;
            S += red[t * 32 + slot];
            W += red[2048 + t * 32 + slot];
        }
        out[px0 + t] = W / S;
    }
}

extern "C" void kernel_launch(void* const* d_in, const int* in_sizes, int n_in,
                              void* d_out, int out_size, void* d_ws, size_t ws_size,
                              hipStream_t stream) {
    const float* qry   = (const float*)d_in[0];   // 256*16384
    const float* sup_x = (const float*)d_in[1];   // 5*256*16384
    const float* sup_y = (const float*)d_in[2];   // 5*16384
    float* out = (float*)d_out;                   // 16384

    char* ws = (char*)d_ws;
    float*     cand_T = (float*)ws;               ws += 256 * 1280 * 4;    // 1.25 MB
    float*     yv_ws  = (float*)ws;               ws += 1280 * 4;
    float*     maskf  = (float*)ws;               ws += 1280 * 4;
    _Float16*  pro_h  = (_Float16*)ws;            /* 640 KB */

    pool_kernel<<<1285, 256, 0, stream>>>(sup_x, sup_y, cand_T, yv_ws);
    fin_kernel<<<21, 256, 0, stream>>>(cand_T, yv_ws, pro_h, maskf);
    main_kernel<<<256, 512, 0, stream>>>(qry, pro_h, maskf, out);
}